// Round 1
// baseline (1259.547 us; speedup 1.0000x reference)
//
#include <hip/hip_runtime.h>
#include <cstdint>

// ---------------- problem constants ----------------
// SEQ=386 tokens, n=384, NP1=385 rows in f/b1, H=256, 4H=1024, EMB=128
#define SEQ   386
#define NP1   385
#define HDIM  256
#define G4    1024
#define EMBD  128
#define LABV  128
#define OUTC  129   // 128 label + 1 split

typedef _Float16 h2 __attribute__((ext_vector_type(2)));

__device__ __forceinline__ uint32_t pack2(float a, float b) {
    h2 v; v[0] = (_Float16)a; v[1] = (_Float16)b;
    return __builtin_bit_cast(uint32_t, v);
}

__device__ __forceinline__ float dot2(uint32_t wa, uint32_t hb, float c) {
    h2 a = __builtin_bit_cast(h2, wa);
    h2 b = __builtin_bit_cast(h2, hb);
#if __has_builtin(__builtin_amdgcn_fdot2)
    return __builtin_amdgcn_fdot2(a, b, c, false);
#else
    return fmaf((float)a[1], (float)b[1], fmaf((float)a[0], (float)b[0], c));
#endif
}

__device__ __forceinline__ float sigm(float x) { return 1.f / (1.f + __expf(-x)); }

// ---------------- workspace layout (bytes) ----------------
#define OFF_EMB   0u                       // 386*128*4      = 197632
#define OFF_GX    197632u                  // 2*386*1024*4   = 3162112
#define OFF_WREG  3359744u                 // 2*24*1024*16   = 786432  (uint4, 16B aligned)
#define OFF_WLDS  4146176u                 // 2*1024*32*4    = 262144
#define OFF_F     4408320u                 // 385*256*4      = 394240
#define OFF_B     4802560u                 // 385*256*4      = 394240
#define OFF_DL    5196800u                 // 385*256*4      = 394240
#define OFF_DS    5591040u                 // 385*256*4      = 394240
#define OFF_W2T   5985280u                 // 256*128*4      = 131072
// total ~6.12 MB

// ---------------- K1: embedding gather ----------------
__global__ void k_embed(const int* __restrict__ tag_ids, const int* __restrict__ word_ids,
                        const float* __restrict__ tag_emb, const float* __restrict__ word_emb,
                        float* __restrict__ emb) {
    int t = blockIdx.x, d = threadIdx.x;
    emb[t * EMBD + d] = tag_emb[tag_ids[t] * EMBD + d] + word_emb[word_ids[t] * EMBD + d];
}

// ---------------- K2: Gx[dir][t][1024] = Wx @ emb[t] + b ----------------
__global__ __launch_bounds__(256) void k_gx(const float* __restrict__ emb,
                                            const float* __restrict__ wxf, const float* __restrict__ bf_,
                                            const float* __restrict__ wxb, const float* __restrict__ bb_,
                                            float* __restrict__ gx) {
    const int dir = blockIdx.y;
    const int t0  = blockIdx.x * 8;
    const float* Wx   = dir ? wxb : wxf;
    const float* bias = dir ? bb_ : bf_;
    __shared__ float se[8 * EMBD];
    for (int idx = threadIdx.x; idx < 8 * EMBD; idx += 256) {
        int tt = t0 + (idx >> 7);
        se[idx] = (tt < SEQ) ? emb[tt * EMBD + (idx & 127)] : 0.f;
    }
    __syncthreads();
    const float4* se4 = (const float4*)se;
    for (int q = 0; q < 4; ++q) {
        int r = threadIdx.x + q * 256;
        float bv = bias[r];
        float acc[8];
#pragma unroll
        for (int tt = 0; tt < 8; ++tt) acc[tt] = bv;
        const float4* wrow = (const float4*)(Wx + r * EMBD);
        for (int d4 = 0; d4 < 32; ++d4) {
            float4 w = wrow[d4];
#pragma unroll
            for (int tt = 0; tt < 8; ++tt) {
                float4 e = se4[tt * 32 + d4];
                acc[tt] += w.x * e.x + w.y * e.y + w.z * e.z + w.w * e.w;
            }
        }
        for (int tt = 0; tt < 8; ++tt) {
            int t = t0 + tt;
            if (t < SEQ) gx[(dir * SEQ + t) * G4 + r] = acc[tt];
        }
    }
}

// ---------------- K3: convert Wh fp32 -> f16 packed layouts ----------------
// reg part:  wreg[dir][cg*1024 + r] (uint4) = cols 8cg..8cg+7 of row r   (cg 0..23, cols 0..191)
// lds part:  wlds[dir][r*32 + c]    (uint32)= cols 192+2c, 193+2c       (c 0..31)
__global__ void k_wconv(const float* __restrict__ whf, const float* __restrict__ whb,
                        uint4* __restrict__ wreg, uint32_t* __restrict__ wlds) {
    const int dir = blockIdx.x;
    const float* Wh = dir ? whb : whf;
    const int y = blockIdx.y, tid = threadIdx.x;
    if (y < 96) {
        int idx = y * 256 + tid;          // [0, 24576)
        int r = idx / 24, cg = idx % 24;
        const float* src = Wh + r * HDIM + cg * 8;
        uint4 o;
        o.x = pack2(src[0], src[1]); o.y = pack2(src[2], src[3]);
        o.z = pack2(src[4], src[5]); o.w = pack2(src[6], src[7]);
        wreg[dir * 24576 + cg * 1024 + r] = o;
    } else {
        int idx = (y - 96) * 256 + tid;   // [0, 32768)
        int r = idx >> 5, c = idx & 31;
        wlds[dir * 32768 + r * 32 + c] = pack2(Wh[r * HDIM + 192 + 2 * c], Wh[r * HDIM + 193 + 2 * c]);
    }
}

// ---------------- K4: the two LSTMs (1 block per direction) ----------------
__global__ __launch_bounds__(1024) void k_lstm(const uint4* __restrict__ wreg,
                                               const uint32_t* __restrict__ wlds,
                                               const float* __restrict__ gx,
                                               float* __restrict__ fout, float* __restrict__ bout) {
    const int dir = blockIdx.x;
    const int tid = threadIdx.x;
    __shared__ uint32_t wl[1024 * 36];            // 147456 B, stride 36 words (16B aligned rows)
    __shared__ float gbuf[1024];
    __shared__ __align__(16) uint32_t hsh[136];   // 256 f16 h values (128 uint32) + pad

    // stage LDS-resident weight columns (cols 192..255)
    const uint32_t* wsrc = wlds + dir * 32768;
    for (int idx = tid; idx < 32768; idx += 1024)
        wl[(idx >> 5) * 36 + (idx & 31)] = wsrc[idx];
    if (tid < 136) hsh[tid] = 0u;

    // register-resident weight columns (cols 0..191): 24 x uint4 = 96 VGPRs
    uint4 w[24];
    const uint4* wr = wreg + dir * 24576;
#pragma unroll
    for (int g = 0; g < 24; ++g) w[g] = wr[g * 1024 + tid];

    const float* gxd = gx + dir * SEQ * G4;
    float c = 0.f;
    float gxv = gxd[(dir ? (SEQ - 1) : 0) * G4 + tid];
    __syncthreads();

    const uint4* h4 = (const uint4*)hsh;
    const uint4* wlrow = (const uint4*)(wl + tid * 36);

    for (int s = 0; s < SEQ; ++s) {
        int t = dir ? (SEQ - 1 - s) : s;
        float gx_next = 0.f;
        if (s < SEQ - 1) {
            int tn = dir ? (SEQ - 2 - s) : (s + 1);
            gx_next = gxd[tn * G4 + tid];
        }
        float acc = gxv;
#pragma unroll
        for (int g = 0; g < 24; ++g) {
            uint4 hv = h4[g];
            acc = dot2(w[g].x, hv.x, acc);
            acc = dot2(w[g].y, hv.y, acc);
            acc = dot2(w[g].z, hv.z, acc);
            acc = dot2(w[g].w, hv.w, acc);
        }
#pragma unroll
        for (int g = 0; g < 8; ++g) {
            uint4 hv = h4[24 + g];
            uint4 wv = wlrow[g];
            acc = dot2(wv.x, hv.x, acc);
            acc = dot2(wv.y, hv.y, acc);
            acc = dot2(wv.z, hv.z, acc);
            acc = dot2(wv.w, hv.w, acc);
        }
        gbuf[tid] = acc;
        __syncthreads();
        if (tid < HDIM) {
            float gi = gbuf[tid];
            float gf = gbuf[tid + 256];
            float gg = gbuf[tid + 512];
            float go = gbuf[tid + 768];
            c = sigm(gf) * c + sigm(gi) * tanhf(gg);
            float h = sigm(go) * tanhf(c);
            ((_Float16*)hsh)[tid] = (_Float16)h;
            if (!dir) { if (t < NP1) fout[t * HDIM + tid] = h; }
            else      { if (t >= 1)  bout[(t - 1) * HDIM + tid] = h; }
        }
        __syncthreads();
        gxv = gx_next;
    }
}

// ---------------- K5: D matrices  D[t,k] = f[t]@w1[:, :256]^T - b1[t]@w1[:,256:]^T ----------------
__global__ __launch_bounds__(256) void k_dmat(const float* __restrict__ fm, const float* __restrict__ bm,
                                              const float* __restrict__ lw1, const float* __restrict__ sw1,
                                              float* __restrict__ dlab, float* __restrict__ dspl) {
    const int t0 = blockIdx.x * 8;
    const int tid = threadIdx.x;
    __shared__ float fs[8 * HDIM], bs[8 * HDIM];
    for (int idx = tid; idx < 8 * HDIM; idx += 256) {
        int tt = t0 + (idx >> 8);
        float fv = 0.f, bv = 0.f;
        if (tt < NP1) { fv = fm[tt * HDIM + (idx & 255)]; bv = bm[tt * HDIM + (idx & 255)]; }
        fs[idx] = fv; bs[idx] = bv;
    }
    __syncthreads();
    float al[8], asp[8];
#pragma unroll
    for (int q = 0; q < 8; ++q) { al[q] = 0.f; asp[q] = 0.f; }
    const float4* lrow = (const float4*)(lw1 + tid * 512);
    const float4* srow = (const float4*)(sw1 + tid * 512);
    const float4* fs4 = (const float4*)fs;
    const float4* bs4 = (const float4*)bs;
    for (int d4 = 0; d4 < 64; ++d4) {
        float4 wlv = lrow[d4], wsv = srow[d4];
#pragma unroll
        for (int tt = 0; tt < 8; ++tt) {
            float4 e = fs4[tt * 64 + d4];
            al[tt]  += wlv.x * e.x + wlv.y * e.y + wlv.z * e.z + wlv.w * e.w;
            asp[tt] += wsv.x * e.x + wsv.y * e.y + wsv.z * e.z + wsv.w * e.w;
        }
    }
    for (int d4 = 0; d4 < 64; ++d4) {
        float4 wlv = lrow[64 + d4], wsv = srow[64 + d4];
#pragma unroll
        for (int tt = 0; tt < 8; ++tt) {
            float4 e = bs4[tt * 64 + d4];
            al[tt]  -= wlv.x * e.x + wlv.y * e.y + wlv.z * e.z + wlv.w * e.w;
            asp[tt] -= wsv.x * e.x + wsv.y * e.y + wsv.z * e.z + wsv.w * e.w;
        }
    }
    for (int tt = 0; tt < 8; ++tt) {
        int t = t0 + tt;
        if (t < NP1) { dlab[t * HDIM + tid] = al[tt]; dspl[t * HDIM + tid] = asp[tt]; }
    }
}

// ---------------- K6: transpose lab_w2 (128x256) -> w2t (256x128) ----------------
__global__ void k_w2t(const float* __restrict__ lw2, float* __restrict__ w2t) {
    int m = blockIdx.x, k = threadIdx.x;
    w2t[k * LABV + m] = lw2[m * HDIM + k];
}

// ---------------- K7: fused output kernel ----------------
// block = (jt, i); 256 threads; computes out[i, jt*32 .. jt*32+31, 0..128]
__global__ __launch_bounds__(256) void k_out(const float* __restrict__ dlab, const float* __restrict__ dspl,
                                             const float* __restrict__ lb1, const float* __restrict__ sb1,
                                             const float* __restrict__ w2t, const float* __restrict__ lb2,
                                             const float* __restrict__ sw2, const float* __restrict__ sb2,
                                             float* __restrict__ outp) {
    const int i = blockIdx.y, jt = blockIdx.x, tid = threadIdx.x;
    __shared__ float dli[HDIM], dsi[HDIM];
    __shared__ float hl[32][257];

    dli[tid] = dlab[i * HDIM + tid] - lb1[tid];
    dsi[tid] = dspl[i * HDIM + tid] - sb1[tid];
    __syncthreads();

    // phase 1: hidden activations for the label MLP (32 j-rows)
    for (int j = 0; j < 32; ++j) {
        int jj = jt * 32 + j;
        float v = 0.f;
        if (jj < NP1) v = fmaxf(dlab[jj * HDIM + tid] - dli[tid], 0.f);
        hl[j][tid] = v;
    }

    // phase 1.5: split scores (per-wave: 4 waves x 8 j each)
    {
        int w = tid >> 6, l = tid & 63;
        float sw2v[4];
#pragma unroll
        for (int cc = 0; cc < 4; ++cc) sw2v[cc] = sw2[l + 64 * cc];
        float sb2v = sb2[0];
        for (int q = 0; q < 8; ++q) {
            int j = w * 8 + q;
            int jj = jt * 32 + j;
            if (jj < NP1) {
                float sum = 0.f;
#pragma unroll
                for (int cc = 0; cc < 4; ++cc) {
                    int k = l + 64 * cc;
                    float v = fmaxf(dspl[jj * HDIM + k] - dsi[k], 0.f);
                    sum += v * sw2v[cc];
                }
#pragma unroll
                for (int off = 32; off > 0; off >>= 1) sum += __shfl_down(sum, off, 64);
                if (l == 0) outp[(size_t)(i * NP1 + jj) * OUTC + 128] = sum + sb2v;
            }
        }
    }
    __syncthreads();

    // phase 2: label GEMM  (32j x 256k) @ (256k x 128m)
    const int tm = tid & 15, tj = tid >> 4;
    const int m0 = tm * 8;
    float acc0[8], acc1[8];
#pragma unroll
    for (int q = 0; q < 8; ++q) { acc0[q] = 0.f; acc1[q] = 0.f; }
    for (int k = 0; k < 256; ++k) {
        const float4* wrow = (const float4*)(w2t + k * LABV + m0);
        float4 wa = wrow[0], wb = wrow[1];
        float a0 = hl[tj][k], a1 = hl[tj + 16][k];
        acc0[0] += a0 * wa.x; acc0[1] += a0 * wa.y; acc0[2] += a0 * wa.z; acc0[3] += a0 * wa.w;
        acc0[4] += a0 * wb.x; acc0[5] += a0 * wb.y; acc0[6] += a0 * wb.z; acc0[7] += a0 * wb.w;
        acc1[0] += a1 * wa.x; acc1[1] += a1 * wa.y; acc1[2] += a1 * wa.z; acc1[3] += a1 * wa.w;
        acc1[4] += a1 * wb.x; acc1[5] += a1 * wb.y; acc1[6] += a1 * wb.z; acc1[7] += a1 * wb.w;
    }
    float bsv[8];
#pragma unroll
    for (int q = 0; q < 8; ++q) bsv[q] = lb2[m0 + q];
    int jj0 = jt * 32 + tj, jj1 = jj0 + 16;
    if (jj0 < NP1) {
        float* o = outp + (size_t)(i * NP1 + jj0) * OUTC + m0;
#pragma unroll
        for (int q = 0; q < 8; ++q) o[q] = acc0[q] + bsv[q];
    }
    if (jj1 < NP1) {
        float* o = outp + (size_t)(i * NP1 + jj1) * OUTC + m0;
#pragma unroll
        for (int q = 0; q < 8; ++q) o[q] = acc1[q] + bsv[q];
    }
}

// ---------------- launcher ----------------
extern "C" void kernel_launch(void* const* d_in, const int* in_sizes, int n_in,
                              void* d_out, int out_size, void* d_ws, size_t ws_size,
                              hipStream_t stream) {
    const int*   tag_ids  = (const int*)d_in[0];
    const int*   word_ids = (const int*)d_in[1];
    const float* tag_emb  = (const float*)d_in[2];
    const float* word_emb = (const float*)d_in[3];
    const float* wxf = (const float*)d_in[4];
    const float* whf = (const float*)d_in[5];
    const float* bf_ = (const float*)d_in[6];
    const float* wxb = (const float*)d_in[7];
    const float* whb = (const float*)d_in[8];
    const float* bb_ = (const float*)d_in[9];
    const float* lw1 = (const float*)d_in[10];
    const float* lb1 = (const float*)d_in[11];
    const float* lw2 = (const float*)d_in[12];
    const float* lb2 = (const float*)d_in[13];
    const float* sw1 = (const float*)d_in[14];
    const float* sb1 = (const float*)d_in[15];
    const float* sw2 = (const float*)d_in[16];
    const float* sb2 = (const float*)d_in[17];

    char* ws = (char*)d_ws;
    float*    emb  = (float*)(ws + OFF_EMB);
    float*    gx   = (float*)(ws + OFF_GX);
    uint4*    wreg = (uint4*)(ws + OFF_WREG);
    uint32_t* wlds = (uint32_t*)(ws + OFF_WLDS);
    float*    fm   = (float*)(ws + OFF_F);
    float*    bm   = (float*)(ws + OFF_B);
    float*    dlab = (float*)(ws + OFF_DL);
    float*    dspl = (float*)(ws + OFF_DS);
    float*    w2t  = (float*)(ws + OFF_W2T);
    float*    outp = (float*)d_out;

    k_embed<<<dim3(SEQ), dim3(EMBD), 0, stream>>>(tag_ids, word_ids, tag_emb, word_emb, emb);
    k_gx   <<<dim3(49, 2), dim3(256), 0, stream>>>(emb, wxf, bf_, wxb, bb_, gx);
    k_wconv<<<dim3(2, 224), dim3(256), 0, stream>>>(whf, whb, wreg, wlds);
    k_w2t  <<<dim3(LABV), dim3(HDIM), 0, stream>>>(lw2, w2t);
    k_lstm <<<dim3(2), dim3(1024), 0, stream>>>(wreg, wlds, gx, fm, bm);
    k_dmat <<<dim3(49), dim3(256), 0, stream>>>(fm, bm, lw1, sw1, dlab, dspl);
    k_out  <<<dim3(13, NP1), dim3(256), 0, stream>>>(dlab, dspl, lb1, sb1, w2t, lb2, sw2, sb2, outp);
}

// Round 2
// 1176.729 us; speedup vs baseline: 1.0704x; 1.0704x over previous
//
#include <hip/hip_runtime.h>
#include <cstdint>

// ---------------- problem constants ----------------
// SEQ=386 tokens, n=384, NP1=385 rows in f/b1, H=256, 4H=1024, EMB=128
#define SEQ   386
#define NP1   385
#define HDIM  256
#define G4    1024
#define EMBD  128
#define LABV  128
#define OUTC  129   // 128 label + 1 split

typedef _Float16 h2 __attribute__((ext_vector_type(2)));

__device__ __forceinline__ uint32_t pack2(float a, float b) {
    h2 v; v[0] = (_Float16)a; v[1] = (_Float16)b;
    return __builtin_bit_cast(uint32_t, v);
}

__device__ __forceinline__ float dot2(uint32_t wa, uint32_t hb, float c) {
    h2 a = __builtin_bit_cast(h2, wa);
    h2 b = __builtin_bit_cast(h2, hb);
#if __has_builtin(__builtin_amdgcn_fdot2)
    return __builtin_amdgcn_fdot2(a, b, c, false);
#else
    return fmaf((float)a[1], (float)b[1], fmaf((float)a[0], (float)b[0], c));
#endif
}

__device__ __forceinline__ float sigm(float x) { return 1.f / (1.f + __expf(-x)); }

// ---------------- workspace layout (bytes) ----------------
#define OFF_EMB   0u                       // 386*128*4      = 197632
#define OFF_GX    197632u                  // 2*386*1024*4   = 3162112
#define OFF_WREG  3359744u                 // 2*24*1024*16   = 786432  (uint4, 16B aligned)
#define OFF_WLDS  4146176u                 // 2*1024*32*4    = 262144
#define OFF_F     4408320u                 // 385*256*4      = 394240
#define OFF_B     4802560u                 // 385*256*4      = 394240
#define OFF_DL    5196800u                 // 385*256*4      = 394240
#define OFF_DS    5591040u                 // 385*256*4      = 394240
#define OFF_W2T   5985280u                 // 256*128*4      = 131072
// total ~6.12 MB

// ---------------- K1: embedding gather ----------------
__global__ void k_embed(const int* __restrict__ tag_ids, const int* __restrict__ word_ids,
                        const float* __restrict__ tag_emb, const float* __restrict__ word_emb,
                        float* __restrict__ emb) {
    int t = blockIdx.x, d = threadIdx.x;
    emb[t * EMBD + d] = tag_emb[tag_ids[t] * EMBD + d] + word_emb[word_ids[t] * EMBD + d];
}

// ---------------- K2: Gx[dir][t][1024] = Wx @ emb[t] + b ----------------
__global__ __launch_bounds__(256) void k_gx(const float* __restrict__ emb,
                                            const float* __restrict__ wxf, const float* __restrict__ bf_,
                                            const float* __restrict__ wxb, const float* __restrict__ bb_,
                                            float* __restrict__ gx) {
    const int dir = blockIdx.y;
    const int t0  = blockIdx.x * 8;
    const float* Wx   = dir ? wxb : wxf;
    const float* bias = dir ? bb_ : bf_;
    __shared__ float se[8 * EMBD];
    for (int idx = threadIdx.x; idx < 8 * EMBD; idx += 256) {
        int tt = t0 + (idx >> 7);
        se[idx] = (tt < SEQ) ? emb[tt * EMBD + (idx & 127)] : 0.f;
    }
    __syncthreads();
    const float4* se4 = (const float4*)se;
    for (int q = 0; q < 4; ++q) {
        int r = threadIdx.x + q * 256;
        float bv = bias[r];
        float acc[8];
#pragma unroll
        for (int tt = 0; tt < 8; ++tt) acc[tt] = bv;
        const float4* wrow = (const float4*)(Wx + r * EMBD);
        for (int d4 = 0; d4 < 32; ++d4) {
            float4 w = wrow[d4];
#pragma unroll
            for (int tt = 0; tt < 8; ++tt) {
                float4 e = se4[tt * 32 + d4];
                acc[tt] += w.x * e.x + w.y * e.y + w.z * e.z + w.w * e.w;
            }
        }
        for (int tt = 0; tt < 8; ++tt) {
            int t = t0 + tt;
            if (t < SEQ) gx[(dir * SEQ + t) * G4 + r] = acc[tt];
        }
    }
}

// ---------------- K3: convert Wh fp32 -> f16 packed layouts ----------------
// reg part:  wreg[dir][cg*1024 + r] (uint4) = cols 8cg..8cg+7 of row r   (cg 0..23, cols 0..191)
// lds part:  wlds[dir][r*32 + c]    (uint32)= cols 192+2c, 193+2c       (c 0..31)
__global__ void k_wconv(const float* __restrict__ whf, const float* __restrict__ whb,
                        uint4* __restrict__ wreg, uint32_t* __restrict__ wlds) {
    const int dir = blockIdx.x;
    const float* Wh = dir ? whb : whf;
    const int y = blockIdx.y, tid = threadIdx.x;
    if (y < 96) {
        int idx = y * 256 + tid;          // [0, 24576)
        int r = idx / 24, cg = idx % 24;
        const float* src = Wh + r * HDIM + cg * 8;
        uint4 o;
        o.x = pack2(src[0], src[1]); o.y = pack2(src[2], src[3]);
        o.z = pack2(src[4], src[5]); o.w = pack2(src[6], src[7]);
        wreg[dir * 24576 + cg * 1024 + r] = o;
    } else {
        int idx = (y - 96) * 256 + tid;   // [0, 32768)
        int r = idx >> 5, c = idx & 31;
        wlds[dir * 32768 + r * 32 + c] = pack2(Wh[r * HDIM + 192 + 2 * c], Wh[r * HDIM + 193 + 2 * c]);
    }
}

// ---------------- K4: the two LSTMs (1 block per direction, 512 threads) ----------------
// Thread owns gate rows {tid, tid+512}. Cols 0..191 of both rows register-resident
// (48 uint4 = 192 VGPRs; __launch_bounds__(512,2) -> 256 VGPR cap, fits with slack).
// Cols 192..255 of all 1024 rows in LDS (stride 36 words, measured 0 conflicts).
__global__ __launch_bounds__(512, 2) void k_lstm(const uint4* __restrict__ wreg,
                                                 const uint32_t* __restrict__ wlds,
                                                 const float* __restrict__ gx,
                                                 float* __restrict__ fout, float* __restrict__ bout) {
    const int dir = blockIdx.x;
    const int tid = threadIdx.x;                  // 0..511
    __shared__ uint32_t wl[1024 * 36];            // 147456 B
    __shared__ float gbuf[1024];
    __shared__ __align__(16) uint32_t hsh[136];   // 256 f16 h values (128 uint32) + pad

    // stage LDS-resident weight columns (cols 192..255)
    const uint32_t* wsrc = wlds + dir * 32768;
    for (int idx = tid; idx < 32768; idx += 512)
        wl[(idx >> 5) * 36 + (idx & 31)] = wsrc[idx];
    if (tid < 136) hsh[tid] = 0u;

    // register-resident weight columns (cols 0..191) for both owned rows
    uint4 w0[24], w1[24];
    const uint4* wr = wreg + dir * 24576;
#pragma unroll
    for (int g = 0; g < 24; ++g) {
        w0[g] = wr[g * 1024 + tid];
        w1[g] = wr[g * 1024 + tid + 512];
    }

    const float* gxd = gx + dir * SEQ * G4;
    float c = 0.f;
    const int tfirst = dir ? (SEQ - 1) : 0;
    float gxv0 = gxd[tfirst * G4 + tid];
    float gxv1 = gxd[tfirst * G4 + tid + 512];
    __syncthreads();

    const uint4* h4 = (const uint4*)hsh;
    const uint4* wlr0 = (const uint4*)(wl + tid * 36);
    const uint4* wlr1 = (const uint4*)(wl + (tid + 512) * 36);

    for (int s = 0; s < SEQ; ++s) {
        int t = dir ? (SEQ - 1 - s) : s;
        float gn0 = 0.f, gn1 = 0.f;
        if (s < SEQ - 1) {
            int tn = dir ? (SEQ - 2 - s) : (s + 1);
            gn0 = gxd[tn * G4 + tid];
            gn1 = gxd[tn * G4 + tid + 512];
        }
        float a0 = gxv0, a1 = gxv1;
#pragma unroll
        for (int g = 0; g < 24; ++g) {
            uint4 hv = h4[g];
            a0 = dot2(w0[g].x, hv.x, a0);
            a0 = dot2(w0[g].y, hv.y, a0);
            a0 = dot2(w0[g].z, hv.z, a0);
            a0 = dot2(w0[g].w, hv.w, a0);
            a1 = dot2(w1[g].x, hv.x, a1);
            a1 = dot2(w1[g].y, hv.y, a1);
            a1 = dot2(w1[g].z, hv.z, a1);
            a1 = dot2(w1[g].w, hv.w, a1);
        }
#pragma unroll
        for (int g = 0; g < 8; ++g) {
            uint4 hv = h4[24 + g];
            uint4 v0 = wlr0[g];
            uint4 v1 = wlr1[g];
            a0 = dot2(v0.x, hv.x, a0);
            a0 = dot2(v0.y, hv.y, a0);
            a0 = dot2(v0.z, hv.z, a0);
            a0 = dot2(v0.w, hv.w, a0);
            a1 = dot2(v1.x, hv.x, a1);
            a1 = dot2(v1.y, hv.y, a1);
            a1 = dot2(v1.z, hv.z, a1);
            a1 = dot2(v1.w, hv.w, a1);
        }
        gbuf[tid] = a0;
        gbuf[tid + 512] = a1;
        __syncthreads();
        if (tid < HDIM) {
            float gi = gbuf[tid];
            float gf = gbuf[tid + 256];
            float gg = gbuf[tid + 512];
            float go = gbuf[tid + 768];
            c = sigm(gf) * c + sigm(gi) * tanhf(gg);
            float h = sigm(go) * tanhf(c);
            ((_Float16*)hsh)[tid] = (_Float16)h;
            if (!dir) { if (t < NP1) fout[t * HDIM + tid] = h; }
            else      { if (t >= 1)  bout[(t - 1) * HDIM + tid] = h; }
        }
        __syncthreads();
        gxv0 = gn0;
        gxv1 = gn1;
    }
}

// ---------------- K5: D matrices  D[t,k] = f[t]@w1[:, :256]^T - b1[t]@w1[:,256:]^T ----------------
__global__ __launch_bounds__(256) void k_dmat(const float* __restrict__ fm, const float* __restrict__ bm,
                                              const float* __restrict__ lw1, const float* __restrict__ sw1,
                                              float* __restrict__ dlab, float* __restrict__ dspl) {
    const int t0 = blockIdx.x * 8;
    const int tid = threadIdx.x;
    __shared__ float fs[8 * HDIM], bs[8 * HDIM];
    for (int idx = tid; idx < 8 * HDIM; idx += 256) {
        int tt = t0 + (idx >> 8);
        float fv = 0.f, bv = 0.f;
        if (tt < NP1) { fv = fm[tt * HDIM + (idx & 255)]; bv = bm[tt * HDIM + (idx & 255)]; }
        fs[idx] = fv; bs[idx] = bv;
    }
    __syncthreads();
    float al[8], asp[8];
#pragma unroll
    for (int q = 0; q < 8; ++q) { al[q] = 0.f; asp[q] = 0.f; }
    const float4* lrow = (const float4*)(lw1 + tid * 512);
    const float4* srow = (const float4*)(sw1 + tid * 512);
    const float4* fs4 = (const float4*)fs;
    const float4* bs4 = (const float4*)bs;
    for (int d4 = 0; d4 < 64; ++d4) {
        float4 wlv = lrow[d4], wsv = srow[d4];
#pragma unroll
        for (int tt = 0; tt < 8; ++tt) {
            float4 e = fs4[tt * 64 + d4];
            al[tt]  += wlv.x * e.x + wlv.y * e.y + wlv.z * e.z + wlv.w * e.w;
            asp[tt] += wsv.x * e.x + wsv.y * e.y + wsv.z * e.z + wsv.w * e.w;
        }
    }
    for (int d4 = 0; d4 < 64; ++d4) {
        float4 wlv = lrow[64 + d4], wsv = srow[64 + d4];
#pragma unroll
        for (int tt = 0; tt < 8; ++tt) {
            float4 e = bs4[tt * 64 + d4];
            al[tt]  -= wlv.x * e.x + wlv.y * e.y + wlv.z * e.z + wlv.w * e.w;
            asp[tt] -= wsv.x * e.x + wsv.y * e.y + wsv.z * e.z + wsv.w * e.w;
        }
    }
    for (int tt = 0; tt < 8; ++tt) {
        int t = t0 + tt;
        if (t < NP1) { dlab[t * HDIM + tid] = al[tt]; dspl[t * HDIM + tid] = asp[tt]; }
    }
}

// ---------------- K6: transpose lab_w2 (128x256) -> w2t (256x128) ----------------
__global__ void k_w2t(const float* __restrict__ lw2, float* __restrict__ w2t) {
    int m = blockIdx.x, k = threadIdx.x;
    w2t[k * LABV + m] = lw2[m * HDIM + k];
}

// ---------------- K7: fused output kernel ----------------
// block = (jt, i); 256 threads; computes out[i, jt*32 .. jt*32+31, 0..128]
__global__ __launch_bounds__(256) void k_out(const float* __restrict__ dlab, const float* __restrict__ dspl,
                                             const float* __restrict__ lb1, const float* __restrict__ sb1,
                                             const float* __restrict__ w2t, const float* __restrict__ lb2,
                                             const float* __restrict__ sw2, const float* __restrict__ sb2,
                                             float* __restrict__ outp) {
    const int i = blockIdx.y, jt = blockIdx.x, tid = threadIdx.x;
    __shared__ float dli[HDIM], dsi[HDIM];
    __shared__ float hl[32][257];

    dli[tid] = dlab[i * HDIM + tid] - lb1[tid];
    dsi[tid] = dspl[i * HDIM + tid] - sb1[tid];
    __syncthreads();

    // phase 1: hidden activations for the label MLP (32 j-rows)
    for (int j = 0; j < 32; ++j) {
        int jj = jt * 32 + j;
        float v = 0.f;
        if (jj < NP1) v = fmaxf(dlab[jj * HDIM + tid] - dli[tid], 0.f);
        hl[j][tid] = v;
    }

    // phase 1.5: split scores (per-wave: 4 waves x 8 j each)
    {
        int w = tid >> 6, l = tid & 63;
        float sw2v[4];
#pragma unroll
        for (int cc = 0; cc < 4; ++cc) sw2v[cc] = sw2[l + 64 * cc];
        float sb2v = sb2[0];
        for (int q = 0; q < 8; ++q) {
            int j = w * 8 + q;
            int jj = jt * 32 + j;
            if (jj < NP1) {
                float sum = 0.f;
#pragma unroll
                for (int cc = 0; cc < 4; ++cc) {
                    int k = l + 64 * cc;
                    float v = fmaxf(dspl[jj * HDIM + k] - dsi[k], 0.f);
                    sum += v * sw2v[cc];
                }
#pragma unroll
                for (int off = 32; off > 0; off >>= 1) sum += __shfl_down(sum, off, 64);
                if (l == 0) outp[(size_t)(i * NP1 + jj) * OUTC + 128] = sum + sb2v;
            }
        }
    }
    __syncthreads();

    // phase 2: label GEMM  (32j x 256k) @ (256k x 128m)
    const int tm = tid & 15, tj = tid >> 4;
    const int m0 = tm * 8;
    float acc0[8], acc1[8];
#pragma unroll
    for (int q = 0; q < 8; ++q) { acc0[q] = 0.f; acc1[q] = 0.f; }
    for (int k = 0; k < 256; ++k) {
        const float4* wrow = (const float4*)(w2t + k * LABV + m0);
        float4 wa = wrow[0], wb = wrow[1];
        float a0 = hl[tj][k], a1 = hl[tj + 16][k];
        acc0[0] += a0 * wa.x; acc0[1] += a0 * wa.y; acc0[2] += a0 * wa.z; acc0[3] += a0 * wa.w;
        acc0[4] += a0 * wb.x; acc0[5] += a0 * wb.y; acc0[6] += a0 * wb.z; acc0[7] += a0 * wb.w;
        acc1[0] += a1 * wa.x; acc1[1] += a1 * wa.y; acc1[2] += a1 * wa.z; acc1[3] += a1 * wa.w;
        acc1[4] += a1 * wb.x; acc1[5] += a1 * wb.y; acc1[6] += a1 * wb.z; acc1[7] += a1 * wb.w;
    }
    float bsv[8];
#pragma unroll
    for (int q = 0; q < 8; ++q) bsv[q] = lb2[m0 + q];
    int jj0 = jt * 32 + tj, jj1 = jj0 + 16;
    if (jj0 < NP1) {
        float* o = outp + (size_t)(i * NP1 + jj0) * OUTC + m0;
#pragma unroll
        for (int q = 0; q < 8; ++q) o[q] = acc0[q] + bsv[q];
    }
    if (jj1 < NP1) {
        float* o = outp + (size_t)(i * NP1 + jj1) * OUTC + m0;
#pragma unroll
        for (int q = 0; q < 8; ++q) o[q] = acc1[q] + bsv[q];
    }
}

// ---------------- launcher ----------------
extern "C" void kernel_launch(void* const* d_in, const int* in_sizes, int n_in,
                              void* d_out, int out_size, void* d_ws, size_t ws_size,
                              hipStream_t stream) {
    const int*   tag_ids  = (const int*)d_in[0];
    const int*   word_ids = (const int*)d_in[1];
    const float* tag_emb  = (const float*)d_in[2];
    const float* word_emb = (const float*)d_in[3];
    const float* wxf = (const float*)d_in[4];
    const float* whf = (const float*)d_in[5];
    const float* bf_ = (const float*)d_in[6];
    const float* wxb = (const float*)d_in[7];
    const float* whb = (const float*)d_in[8];
    const float* bb_ = (const float*)d_in[9];
    const float* lw1 = (const float*)d_in[10];
    const float* lb1 = (const float*)d_in[11];
    const float* lw2 = (const float*)d_in[12];
    const float* lb2 = (const float*)d_in[13];
    const float* sw1 = (const float*)d_in[14];
    const float* sb1 = (const float*)d_in[15];
    const float* sw2 = (const float*)d_in[16];
    const float* sb2 = (const float*)d_in[17];

    char* ws = (char*)d_ws;
    float*    emb  = (float*)(ws + OFF_EMB);
    float*    gx   = (float*)(ws + OFF_GX);
    uint4*    wreg = (uint4*)(ws + OFF_WREG);
    uint32_t* wlds = (uint32_t*)(ws + OFF_WLDS);
    float*    fm   = (float*)(ws + OFF_F);
    float*    bm   = (float*)(ws + OFF_B);
    float*    dlab = (float*)(ws + OFF_DL);
    float*    dspl = (float*)(ws + OFF_DS);
    float*    w2t  = (float*)(ws + OFF_W2T);
    float*    outp = (float*)d_out;

    k_embed<<<dim3(SEQ), dim3(EMBD), 0, stream>>>(tag_ids, word_ids, tag_emb, word_emb, emb);
    k_gx   <<<dim3(49, 2), dim3(256), 0, stream>>>(emb, wxf, bf_, wxb, bb_, gx);
    k_wconv<<<dim3(2, 224), dim3(256), 0, stream>>>(whf, whb, wreg, wlds);
    k_w2t  <<<dim3(LABV), dim3(HDIM), 0, stream>>>(lw2, w2t);
    k_lstm <<<dim3(2), dim3(512), 0, stream>>>(wreg, wlds, gx, fm, bm);
    k_dmat <<<dim3(49), dim3(256), 0, stream>>>(fm, bm, lw1, sw1, dlab, dspl);
    k_out  <<<dim3(13, NP1), dim3(256), 0, stream>>>(dlab, dspl, lb1, sb1, w2t, lb2, sw2, sb2, outp);
}

// Round 3
// 889.988 us; speedup vs baseline: 1.4152x; 1.3222x over previous
//
#include <hip/hip_runtime.h>
#include <cstdint>

// ---------------- problem constants ----------------
#define SEQ   386
#define NP1   385
#define HDIM  256
#define G4    1024
#define EMBD  128
#define LABV  128
#define OUTC  129   // 128 label + 1 split

typedef _Float16 h2 __attribute__((ext_vector_type(2)));
typedef _Float16 f16x8 __attribute__((ext_vector_type(8)));
typedef float    f32x4 __attribute__((ext_vector_type(4)));

__device__ __forceinline__ uint32_t pack2(float a, float b) {
    h2 v; v[0] = (_Float16)a; v[1] = (_Float16)b;
    return __builtin_bit_cast(uint32_t, v);
}

__device__ __forceinline__ float dot2(uint32_t wa, uint32_t hb, float c) {
    h2 a = __builtin_bit_cast(h2, wa);
    h2 b = __builtin_bit_cast(h2, hb);
#if __has_builtin(__builtin_amdgcn_fdot2)
    return __builtin_amdgcn_fdot2(a, b, c, false);
#else
    return fmaf((float)a[1], (float)b[1], fmaf((float)a[0], (float)b[0], c));
#endif
}

__device__ __forceinline__ float sigm(float x) { return 1.f / (1.f + __expf(-x)); }
__device__ __forceinline__ float ftanh(float x) {
    x = fminf(fmaxf(x, -15.f), 15.f);
    float e = __expf(2.f * x);
    return (e - 1.f) / (e + 1.f);
}

// ---------------- workspace layout (bytes) ----------------
#define OFF_EMB   0u                       // 386*128*4      = 197632
#define OFF_GX    197632u                  // 2*386*1024*4   = 3162112
#define OFF_WREG  3359744u                 // 2*24*1024*16   = 786432
#define OFF_WLDS  4146176u                 // 2*1024*32*4    = 262144
#define OFF_F     4408320u                 // 385*256*4      = 394240
#define OFF_B     4802560u                 // 385*256*4      = 394240
#define OFF_DL    5196800u                 // 385*256*4      = 394240
#define OFF_DS    5591040u                 // 385*256*4      = 394240
#define OFF_W2F   5985280u                 // 32*128*8*2     = 65536 (f16 B-fragments)
// total ~6.05 MB

// ---------------- K1: embedding gather ----------------
__global__ void k_embed(const int* __restrict__ tag_ids, const int* __restrict__ word_ids,
                        const float* __restrict__ tag_emb, const float* __restrict__ word_emb,
                        float* __restrict__ emb) {
    int t = blockIdx.x, d = threadIdx.x;
    emb[t * EMBD + d] = tag_emb[tag_ids[t] * EMBD + d] + word_emb[word_ids[t] * EMBD + d];
}

// ---------------- K2: Gx[dir][t][1024] = Wx @ emb[t] + b ----------------
__global__ __launch_bounds__(256) void k_gx(const float* __restrict__ emb,
                                            const float* __restrict__ wxf, const float* __restrict__ bf_,
                                            const float* __restrict__ wxb, const float* __restrict__ bb_,
                                            float* __restrict__ gx) {
    const int dir = blockIdx.y;
    const int t0  = blockIdx.x * 8;
    const float* Wx   = dir ? wxb : wxf;
    const float* bias = dir ? bb_ : bf_;
    __shared__ float se[8 * EMBD];
    for (int idx = threadIdx.x; idx < 8 * EMBD; idx += 256) {
        int tt = t0 + (idx >> 7);
        se[idx] = (tt < SEQ) ? emb[tt * EMBD + (idx & 127)] : 0.f;
    }
    __syncthreads();
    const float4* se4 = (const float4*)se;
    for (int q = 0; q < 4; ++q) {
        int r = threadIdx.x + q * 256;
        float bv = bias[r];
        float acc[8];
#pragma unroll
        for (int tt = 0; tt < 8; ++tt) acc[tt] = bv;
        const float4* wrow = (const float4*)(Wx + r * EMBD);
        for (int d4 = 0; d4 < 32; ++d4) {
            float4 w = wrow[d4];
#pragma unroll
            for (int tt = 0; tt < 8; ++tt) {
                float4 e = se4[tt * 32 + d4];
                acc[tt] += w.x * e.x + w.y * e.y + w.z * e.z + w.w * e.w;
            }
        }
        for (int tt = 0; tt < 8; ++tt) {
            int t = t0 + tt;
            if (t < SEQ) gx[(dir * SEQ + t) * G4 + r] = acc[tt];
        }
    }
}

// ---------------- K3: convert Wh fp32 -> f16 packed layouts ----------------
__global__ void k_wconv(const float* __restrict__ whf, const float* __restrict__ whb,
                        uint4* __restrict__ wreg, uint32_t* __restrict__ wlds) {
    const int dir = blockIdx.x;
    const float* Wh = dir ? whb : whf;
    const int y = blockIdx.y, tid = threadIdx.x;
    if (y < 96) {
        int idx = y * 256 + tid;          // [0, 24576)
        int r = idx / 24, cg = idx % 24;
        const float* src = Wh + r * HDIM + cg * 8;
        uint4 o;
        o.x = pack2(src[0], src[1]); o.y = pack2(src[2], src[3]);
        o.z = pack2(src[4], src[5]); o.w = pack2(src[6], src[7]);
        wreg[dir * 24576 + cg * 1024 + r] = o;
    } else {
        int idx = (y - 96) * 256 + tid;   // [0, 32768)
        int r = idx >> 5, c = idx & 31;
        wlds[dir * 32768 + r * 32 + c] = pack2(Wh[r * HDIM + 192 + 2 * c], Wh[r * HDIM + 193 + 2 * c]);
    }
}

// ---------------- K4: the two LSTMs (1 block per direction, 512 threads) ----------------
// amdgpu_waves_per_eu(2,2): force the allocator to target 2 waves/EU -> 256 VGPR cap,
// so the 48 weight uint4s (192 VGPRs) stay register-resident across the step loop.
__global__ __launch_bounds__(512)
__attribute__((amdgpu_waves_per_eu(2, 2)))
void k_lstm(const uint4* __restrict__ wreg,
            const uint32_t* __restrict__ wlds,
            const float* __restrict__ gx,
            float* __restrict__ fout, float* __restrict__ bout) {
    const int dir = blockIdx.x;
    const int tid = threadIdx.x;                  // 0..511
    __shared__ uint32_t wl[1024 * 36];            // 147456 B, stride 36 words (even bank spread for b128)
    __shared__ float gbuf[1024];
    __shared__ __align__(16) uint32_t hsh[136];   // 256 f16 h values + pad

    const uint32_t* wsrc = wlds + dir * 32768;
    for (int idx = tid; idx < 32768; idx += 512)
        wl[(idx >> 5) * 36 + (idx & 31)] = wsrc[idx];
    if (tid < 136) hsh[tid] = 0u;

    uint4 w0[24], w1[24];
    const uint4* wr = wreg + dir * 24576;
#pragma unroll
    for (int g = 0; g < 24; ++g) {
        w0[g] = wr[g * 1024 + tid];
        w1[g] = wr[g * 1024 + tid + 512];
    }

    const float* gxd = gx + dir * SEQ * G4;
    float c = 0.f;
    const int tfirst = dir ? (SEQ - 1) : 0;
    float gxv0 = gxd[tfirst * G4 + tid];
    float gxv1 = gxd[tfirst * G4 + tid + 512];
    __syncthreads();

    const uint4* h4 = (const uint4*)hsh;
    const uint4* wlr0 = (const uint4*)(wl + tid * 36);
    const uint4* wlr1 = (const uint4*)(wl + (tid + 512) * 36);

    for (int s = 0; s < SEQ; ++s) {
        int t = dir ? (SEQ - 1 - s) : s;
        float gn0 = 0.f, gn1 = 0.f;
        if (s < SEQ - 1) {
            int tn = dir ? (SEQ - 2 - s) : (s + 1);
            gn0 = gxd[tn * G4 + tid];
            gn1 = gxd[tn * G4 + tid + 512];
        }
        float a0 = gxv0, a1 = gxv1;
#pragma unroll
        for (int g = 0; g < 24; ++g) {
            uint4 hv = h4[g];
            a0 = dot2(w0[g].x, hv.x, a0);
            a0 = dot2(w0[g].y, hv.y, a0);
            a0 = dot2(w0[g].z, hv.z, a0);
            a0 = dot2(w0[g].w, hv.w, a0);
            a1 = dot2(w1[g].x, hv.x, a1);
            a1 = dot2(w1[g].y, hv.y, a1);
            a1 = dot2(w1[g].z, hv.z, a1);
            a1 = dot2(w1[g].w, hv.w, a1);
        }
#pragma unroll
        for (int g = 0; g < 8; ++g) {
            uint4 hv = h4[24 + g];
            uint4 v0 = wlr0[g];
            uint4 v1 = wlr1[g];
            a0 = dot2(v0.x, hv.x, a0);
            a0 = dot2(v0.y, hv.y, a0);
            a0 = dot2(v0.z, hv.z, a0);
            a0 = dot2(v0.w, hv.w, a0);
            a1 = dot2(v1.x, hv.x, a1);
            a1 = dot2(v1.y, hv.y, a1);
            a1 = dot2(v1.z, hv.z, a1);
            a1 = dot2(v1.w, hv.w, a1);
        }
        gbuf[tid] = a0;
        gbuf[tid + 512] = a1;
        __syncthreads();
        if (tid < HDIM) {
            float gi = gbuf[tid];
            float gf = gbuf[tid + 256];
            float gg = gbuf[tid + 512];
            float go = gbuf[tid + 768];
            c = sigm(gf) * c + sigm(gi) * ftanh(gg);
            float h = sigm(go) * ftanh(c);
            ((_Float16*)hsh)[tid] = (_Float16)h;
            if (!dir) { if (t < NP1) fout[t * HDIM + tid] = h; }
            else      { if (t >= 1)  bout[(t - 1) * HDIM + tid] = h; }
        }
        __syncthreads();
        gxv0 = gn0;
        gxv1 = gn1;
    }
}

// ---------------- K5: D matrices ----------------
__global__ __launch_bounds__(256) void k_dmat(const float* __restrict__ fm, const float* __restrict__ bm,
                                              const float* __restrict__ lw1, const float* __restrict__ sw1,
                                              float* __restrict__ dlab, float* __restrict__ dspl) {
    const int t0 = blockIdx.x * 8;
    const int tid = threadIdx.x;
    __shared__ float fs[8 * HDIM], bs[8 * HDIM];
    for (int idx = tid; idx < 8 * HDIM; idx += 256) {
        int tt = t0 + (idx >> 8);
        float fv = 0.f, bv = 0.f;
        if (tt < NP1) { fv = fm[tt * HDIM + (idx & 255)]; bv = bm[tt * HDIM + (idx & 255)]; }
        fs[idx] = fv; bs[idx] = bv;
    }
    __syncthreads();
    float al[8], asp[8];
#pragma unroll
    for (int q = 0; q < 8; ++q) { al[q] = 0.f; asp[q] = 0.f; }
    const float4* lrow = (const float4*)(lw1 + tid * 512);
    const float4* srow = (const float4*)(sw1 + tid * 512);
    const float4* fs4 = (const float4*)fs;
    const float4* bs4 = (const float4*)bs;
    for (int d4 = 0; d4 < 64; ++d4) {
        float4 wlv = lrow[d4], wsv = srow[d4];
#pragma unroll
        for (int tt = 0; tt < 8; ++tt) {
            float4 e = fs4[tt * 64 + d4];
            al[tt]  += wlv.x * e.x + wlv.y * e.y + wlv.z * e.z + wlv.w * e.w;
            asp[tt] += wsv.x * e.x + wsv.y * e.y + wsv.z * e.z + wsv.w * e.w;
        }
    }
    for (int d4 = 0; d4 < 64; ++d4) {
        float4 wlv = lrow[64 + d4], wsv = srow[64 + d4];
#pragma unroll
        for (int tt = 0; tt < 8; ++tt) {
            float4 e = bs4[tt * 64 + d4];
            al[tt]  -= wlv.x * e.x + wlv.y * e.y + wlv.z * e.z + wlv.w * e.w;
            asp[tt] -= wsv.x * e.x + wsv.y * e.y + wsv.z * e.z + wsv.w * e.w;
        }
    }
    for (int tt = 0; tt < 8; ++tt) {
        int t = t0 + tt;
        if (t < NP1) { dlab[t * HDIM + tid] = al[tt]; dspl[t * HDIM + tid] = asp[tt]; }
    }
}

// ---------------- K6: pack lab_w2 into f16 MFMA B-fragments ----------------
// w2f[kb8][m][j] = (f16) lw2[m][kb8*8+j],  kb8=k>>3, j=k&7
__global__ void k_w2f(const float* __restrict__ lw2, _Float16* __restrict__ w2f) {
    int m = blockIdx.x, k = threadIdx.x;
    w2f[(((k >> 3) * LABV) + m) * 8 + (k & 7)] = (_Float16)lw2[m * HDIM + k];
}

// ---------------- K7: fused output kernel (MFMA f16) ----------------
// block = (jt, i); 256 threads (4 waves); out[i, jt*32 .. +31, 0..128]
// wave w owns m-tiles {2w, 2w+1}; both 16-row j-tiles; K=256 in 8 mfma steps.
__global__ __launch_bounds__(256) void k_out(const float* __restrict__ dlab, const float* __restrict__ dspl,
                                             const float* __restrict__ lb1, const float* __restrict__ sb1,
                                             const _Float16* __restrict__ w2f, const float* __restrict__ lb2,
                                             const float* __restrict__ sw2, const float* __restrict__ sb2,
                                             float* __restrict__ outp) {
    const int i = blockIdx.y, jtblk = blockIdx.x, tid = threadIdx.x;
    __shared__ float dli[HDIM], dsi[HDIM];
    __shared__ _Float16 hl[32 * 264];   // row stride 264 f16 (=33*16B) to spread banks

    dli[tid] = dlab[i * HDIM + tid] - lb1[tid];
    dsi[tid] = dspl[i * HDIM + tid] - sb1[tid];
    __syncthreads();

    // phase 1: hidden activations (f16) for the label MLP
    for (int j = 0; j < 32; ++j) {
        int jj = jtblk * 32 + j;
        float v = 0.f;
        if (jj < NP1) v = fmaxf(dlab[jj * HDIM + tid] - dli[tid], 0.f);
        hl[j * 264 + tid] = (_Float16)v;
    }

    // phase 1.5: split scores
    {
        int w = tid >> 6, l = tid & 63;
        float sw2v[4];
#pragma unroll
        for (int cc = 0; cc < 4; ++cc) sw2v[cc] = sw2[l + 64 * cc];
        float sb2v = sb2[0];
        for (int q = 0; q < 8; ++q) {
            int jj = jtblk * 32 + w * 8 + q;
            if (jj < NP1) {
                float sum = 0.f;
#pragma unroll
                for (int cc = 0; cc < 4; ++cc) {
                    int k = l + 64 * cc;
                    float v = fmaxf(dspl[jj * HDIM + k] - dsi[k], 0.f);
                    sum += v * sw2v[cc];
                }
#pragma unroll
                for (int off = 32; off > 0; off >>= 1) sum += __shfl_down(sum, off, 64);
                if (l == 0) outp[(size_t)(i * NP1 + jj) * OUTC + 128] = sum + sb2v;
            }
        }
    }
    __syncthreads();

    // phase 2: label GEMM via mfma_f32_16x16x32_f16
    const int w = tid >> 6, l = tid & 63;
    const int q = l >> 4, c16 = l & 15;
    f32x4 acc[2][2];
#pragma unroll
    for (int a = 0; a < 2; ++a)
#pragma unroll
        for (int b = 0; b < 2; ++b) acc[a][b] = (f32x4){0.f, 0.f, 0.f, 0.f};

    const int mt0 = w * 2;
#pragma unroll
    for (int kb = 0; kb < 8; ++kb) {
        // A-frags: lane holds hl[jt*16 + c16][kb*32 + q*8 .. +7]
        f16x8 a0 = *(const f16x8*)(hl + (0 * 16 + c16) * 264 + kb * 32 + q * 8);
        f16x8 a1 = *(const f16x8*)(hl + (1 * 16 + c16) * 264 + kb * 32 + q * 8);
        // B-frags: lane holds w2f[kb*4+q][mt*16 + c16][0..7]
        f16x8 b0 = *(const f16x8*)(w2f + (((kb * 4 + q) * LABV) + mt0 * 16 + c16) * 8);
        f16x8 b1 = *(const f16x8*)(w2f + (((kb * 4 + q) * LABV) + (mt0 + 1) * 16 + c16) * 8);
        acc[0][0] = __builtin_amdgcn_mfma_f32_16x16x32_f16(a0, b0, acc[0][0], 0, 0, 0);
        acc[0][1] = __builtin_amdgcn_mfma_f32_16x16x32_f16(a0, b1, acc[0][1], 0, 0, 0);
        acc[1][0] = __builtin_amdgcn_mfma_f32_16x16x32_f16(a1, b0, acc[1][0], 0, 0, 0);
        acc[1][1] = __builtin_amdgcn_mfma_f32_16x16x32_f16(a1, b1, acc[1][1], 0, 0, 0);
    }

    // epilogue: C/D layout col = lane&15, row = q*4 + reg
#pragma unroll
    for (int mb = 0; mb < 2; ++mb) {
        int m = (mt0 + mb) * 16 + c16;
        float bias = lb2[m];
#pragma unroll
        for (int jt = 0; jt < 2; ++jt) {
#pragma unroll
            for (int r = 0; r < 4; ++r) {
                int jj = jtblk * 32 + jt * 16 + q * 4 + r;
                if (jj < NP1) outp[(size_t)(i * NP1 + jj) * OUTC + m] = acc[jt][mb][r] + bias;
            }
        }
    }
}

// ---------------- launcher ----------------
extern "C" void kernel_launch(void* const* d_in, const int* in_sizes, int n_in,
                              void* d_out, int out_size, void* d_ws, size_t ws_size,
                              hipStream_t stream) {
    const int*   tag_ids  = (const int*)d_in[0];
    const int*   word_ids = (const int*)d_in[1];
    const float* tag_emb  = (const float*)d_in[2];
    const float* word_emb = (const float*)d_in[3];
    const float* wxf = (const float*)d_in[4];
    const float* whf = (const float*)d_in[5];
    const float* bf_ = (const float*)d_in[6];
    const float* wxb = (const float*)d_in[7];
    const float* whb = (const float*)d_in[8];
    const float* bb_ = (const float*)d_in[9];
    const float* lw1 = (const float*)d_in[10];
    const float* lb1 = (const float*)d_in[11];
    const float* lw2 = (const float*)d_in[12];
    const float* lb2 = (const float*)d_in[13];
    const float* sw1 = (const float*)d_in[14];
    const float* sb1 = (const float*)d_in[15];
    const float* sw2 = (const float*)d_in[16];
    const float* sb2 = (const float*)d_in[17];

    char* ws = (char*)d_ws;
    float*     emb  = (float*)(ws + OFF_EMB);
    float*     gx   = (float*)(ws + OFF_GX);
    uint4*     wreg = (uint4*)(ws + OFF_WREG);
    uint32_t*  wlds = (uint32_t*)(ws + OFF_WLDS);
    float*     fm   = (float*)(ws + OFF_F);
    float*     bm   = (float*)(ws + OFF_B);
    float*     dlab = (float*)(ws + OFF_DL);
    float*     dspl = (float*)(ws + OFF_DS);
    _Float16*  w2f  = (_Float16*)(ws + OFF_W2F);
    float*     outp = (float*)d_out;

    k_embed<<<dim3(SEQ), dim3(EMBD), 0, stream>>>(tag_ids, word_ids, tag_emb, word_emb, emb);
    k_gx   <<<dim3(49, 2), dim3(256), 0, stream>>>(emb, wxf, bf_, wxb, bb_, gx);
    k_wconv<<<dim3(2, 224), dim3(256), 0, stream>>>(whf, whb, wreg, wlds);
    k_w2f  <<<dim3(LABV), dim3(HDIM), 0, stream>>>(lw2, w2f);
    k_lstm <<<dim3(2), dim3(512), 0, stream>>>(wreg, wlds, gx, fm, bm);
    k_dmat <<<dim3(49), dim3(256), 0, stream>>>(fm, bm, lw1, sw1, dlab, dspl);
    k_out  <<<dim3(13, NP1), dim3(256), 0, stream>>>(dlab, dspl, lb1, sb1, w2f, lb2, sw2, sb2, outp);
}